// Round 2
// baseline (279.064 us; speedup 1.0000x reference)
//
#include <hip/hip_runtime.h>

// ---------------------------------------------------------------------------
// LatentMixtureAllRNNAgent: fused per-agent fc1 -> GRU cell -> fc2 on MI355X.
// BS=4096, A=8, IN=H=256, 3H=768, NACT=30. Flat row r -> agent r%8.
// Precision scheme (round 2):
//   fc1: split-bf16 A (inp hi+lo) x split-bf16 W1 (hi+lo), 3 MFMA passes.
//   gates: x (single bf16) & h_in (single bf16) @ CENTERED bf16(W-0.5) planes,
//          exact 0.5*rowsum corrections computed in f32 from the bf16 tiles.
//   fc2: single bf16 (error path harmless).
// ---------------------------------------------------------------------------

typedef __attribute__((ext_vector_type(4))) float f32x4;
typedef __attribute__((ext_vector_type(8))) short s8;     // 8 bf16 (4 VGPRs)
typedef __attribute__((ext_vector_type(4))) unsigned short us4;

#define QSIZE   983040      /* 32768*30 */
#define W1H_OFF 0
#define W1L_OFF 524288
#define WIH_OFF 1048576
#define WHH_OFF 2621440
#define W2T_OFF 4194304

static __device__ __forceinline__ unsigned short f2bf(float f) {
  union { float f; unsigned u; } v; v.f = f;
  unsigned r = v.u + 0x7FFFu + ((v.u >> 16) & 1u);   // RNE
  return (unsigned short)(r >> 16);
}
static __device__ __forceinline__ float bf2f(unsigned short u) {
  union { unsigned u; float f; } v; v.u = ((unsigned)u) << 16;
  return v.f;
}
static __device__ __forceinline__ float sigm(float x) {
  return 1.0f / (1.0f + __expf(-x));
}
static __device__ __forceinline__ float tanh_(float x) {
  return 1.0f - 2.0f / (__expf(2.0f * x) + 1.0f);    // saturates correctly
}

// ------------- prep: f32 [a][k][n] -> bf16 [a][n][k] planes in ws -----------
__global__ void prep_weights(const float* __restrict__ fc1w,
                             const float* __restrict__ rihw,
                             const float* __restrict__ rhhw,
                             const float* __restrict__ fc2w,
                             unsigned short* __restrict__ ws) {
  int q = blockIdx.x * 256 + threadIdx.x;   // one us4 (4 k-values) per thread
  if (q < 131072) {                         // fc1: hi + lo planes
    int a = q >> 14, rem = q & 16383, k4 = rem >> 8, n = rem & 255;
    const float* s = fc1w + a * 65536 + (k4 * 4) * 256 + n;
    float v0 = s[0], v1 = s[256], v2 = s[512], v3 = s[768];
    us4 hi = { f2bf(v0), f2bf(v1), f2bf(v2), f2bf(v3) };
    us4 lo = { f2bf(v0 - bf2f(hi[0])), f2bf(v1 - bf2f(hi[1])),
               f2bf(v2 - bf2f(hi[2])), f2bf(v3 - bf2f(hi[3])) };
    int o = ((a * 256 + n) << 8) + k4 * 4;
    *(us4*)(ws + W1H_OFF + o) = hi;
    *(us4*)(ws + W1L_OFF + o) = lo;
  } else if (q < 524288) {                  // rnn_ih, centered (w - 0.5)
    int t = q - 131072;
    int a = t / 49152, rem = t % 49152, k4 = rem / 768, n = rem % 768;
    const float* s = rihw + a * 196608 + (k4 * 4) * 768 + n;
    us4 v = { f2bf(s[0] - 0.5f), f2bf(s[768] - 0.5f),
              f2bf(s[1536] - 0.5f), f2bf(s[2304] - 0.5f) };
    *(us4*)(ws + WIH_OFF + ((a * 768 + n) << 8) + k4 * 4) = v;
  } else if (q < 917504) {                  // rnn_hh, centered
    int t = q - 524288;
    int a = t / 49152, rem = t % 49152, k4 = rem / 768, n = rem % 768;
    const float* s = rhhw + a * 196608 + (k4 * 4) * 768 + n;
    us4 v = { f2bf(s[0] - 0.5f), f2bf(s[768] - 0.5f),
              f2bf(s[1536] - 0.5f), f2bf(s[2304] - 0.5f) };
    *(us4*)(ws + WHH_OFF + ((a * 768 + n) << 8) + k4 * 4) = v;
  } else if (q < 933888) {                  // fc2: plain, pad 30->32
    int t = q - 917504;
    int a = t >> 11, rem = t & 2047, k4 = rem >> 5, n = rem & 31;
    us4 v = { 0, 0, 0, 0 };
    if (n < 30) {
      const float* s = fc2w + a * 7680 + (k4 * 4) * 30 + n;
      v = (us4){ f2bf(s[0]), f2bf(s[30]), f2bf(s[60]), f2bf(s[90]) };
    }
    *(us4*)(ws + W2T_OFF + ((a * 32 + n) << 8) + k4 * 4) = v;
  }
}

// ------- stage 64x256 f32 tile -> split bf16 (hi plane p0, lo plane p1) -----
static __device__ __forceinline__ void stage_split(unsigned short* p0,
                                                   unsigned short* p1,
                                                   const float* __restrict__ src,
                                                   int rowbase, int a, int tid) {
#pragma unroll
  for (int k = 0; k < 16; ++k) {
    int j = tid + k * 256;
    int r = j >> 6;
    int c4 = (j & 63) << 2;
    const float* p = src + ((((rowbase + r) << 3) + a) << 8) + c4;
    float4 v = *(const float4*)p;
    us4 hi = { f2bf(v.x), f2bf(v.y), f2bf(v.z), f2bf(v.w) };
    us4 lo = { f2bf(v.x - bf2f(hi[0])), f2bf(v.y - bf2f(hi[1])),
               f2bf(v.z - bf2f(hi[2])), f2bf(v.w - bf2f(hi[3])) };
    int idx = ((r << 8) + c4) ^ ((r & 7) << 3);   // XOR swizzle (16B blocks)
    *(us4*)(p0 + idx) = hi;
    *(us4*)(p1 + idx) = lo;
  }
}

// ------------- stage 64x256 f32 tile -> single bf16 plane -------------------
static __device__ __forceinline__ void stage_single(unsigned short* p,
                                                    const float* __restrict__ src,
                                                    int rowbase, int a, int tid) {
#pragma unroll
  for (int k = 0; k < 16; ++k) {
    int j = tid + k * 256;
    int r = j >> 6;
    int c4 = (j & 63) << 2;
    const float* sp = src + ((((rowbase + r) << 3) + a) << 8) + c4;
    float4 v = *(const float4*)sp;
    us4 hi = { f2bf(v.x), f2bf(v.y), f2bf(v.z), f2bf(v.w) };
    int idx = ((r << 8) + c4) ^ ((r & 7) << 3);
    *(us4*)(p + idx) = hi;
  }
}

// ------------- 64x64 output tile GEMM over K=256: acc += A_lds @ Wt^T -------
static __device__ __forceinline__ void mma64(const unsigned short* lds,
                                             const unsigned short* __restrict__ wt,
                                             int n0, int l16, int l4,
                                             f32x4 (&acc)[4][4]) {
#pragma unroll
  for (int ks = 0; ks < 8; ++ks) {
    s8 af[4], bw[4];
#pragma unroll
    for (int mt = 0; mt < 4; ++mt) {
      int row = mt * 16 + l16;
      int idx = ((row << 8) + ks * 32 + 8 * l4) ^ ((row & 7) << 3);
      af[mt] = *(const s8*)(lds + idx);
    }
#pragma unroll
    for (int nt = 0; nt < 4; ++nt) {
      bw[nt] = *(const s8*)(wt + ((n0 + nt * 16 + l16) << 8) + ks * 32 + 8 * l4);
    }
#pragma unroll
    for (int mt = 0; mt < 4; ++mt)
#pragma unroll
      for (int nt = 0; nt < 4; ++nt)
        acc[mt][nt] = __builtin_amdgcn_mfma_f32_16x16x32_bf16(
            af[mt], bw[nt], acc[mt][nt], 0, 0, 0);
  }
}

// ---------------------------- fused main kernel -----------------------------
__global__ __launch_bounds__(256, 2) void fused_agent_rnn(
    const float* __restrict__ inp,  const float* __restrict__ hin,
    const float* __restrict__ b1,   const float* __restrict__ bih,
    const float* __restrict__ bhh,  const float* __restrict__ b2,
    const unsigned short* __restrict__ ws, float* __restrict__ out) {
  __shared__ __align__(16) unsigned short P0[64 * 256];  // inp_hi -> x -> h
  __shared__ __align__(16) unsigned short P1[64 * 256];  // inp_lo -> h_in
  __shared__ float RSXP[4][64], RSHP[4][64];
  __shared__ float RSX[64], RSH[64];                     // rowsum(x), rowsum(h_in)

  const unsigned short* W1H = ws + W1H_OFF;
  const unsigned short* W1L = ws + W1L_OFF;
  const unsigned short* Wih = ws + WIH_OFF;
  const unsigned short* Whh = ws + WHH_OFF;
  const unsigned short* W2t = ws + W2T_OFF;

  const int tid = threadIdx.x;
  const int a = blockIdx.x & 7;          // agent == XCD (round-robin dispatch)
  const int bt = blockIdx.x >> 3;
  const int rowbase = bt * 64;
  const int lane = tid & 63, w = tid >> 6;
  const int l16 = lane & 15, l4 = lane >> 4;
  const int n0 = w * 64;                 // wave's 64-col slice

  // ---- stage inp split; fc1: x = relu(inp @ W1 + b1), 3 split passes ----
  stage_split(P0, P1, inp, rowbase, a, tid);
  __syncthreads();

  f32x4 XA[4][4];
#pragma unroll
  for (int mt = 0; mt < 4; ++mt)
#pragma unroll
    for (int nt = 0; nt < 4; ++nt) XA[mt][nt] = (f32x4){0.f, 0.f, 0.f, 0.f};
  mma64(P0, W1H + a * 65536, n0, l16, l4, XA);   // inp_hi @ W1_hi
  mma64(P1, W1H + a * 65536, n0, l16, l4, XA);   // inp_lo @ W1_hi
  mma64(P0, W1L + a * 65536, n0, l16, l4, XA);   // inp_hi @ W1_lo
  __syncthreads();                                // all fc1 reads done

  // write x (bf16) into P0; stage h_in (bf16) into P1
#pragma unroll
  for (int nt = 0; nt < 4; ++nt) {
    int col = n0 + nt * 16 + l16;
    float bb = b1[a * 256 + col];
#pragma unroll
    for (int mt = 0; mt < 4; ++mt)
#pragma unroll
      for (int r = 0; r < 4; ++r) {
        float v = fmaxf(XA[mt][nt][r] + bb, 0.f);
        int row = mt * 16 + l4 * 4 + r;
        P0[((row << 8) + col) ^ ((row & 7) << 3)] = f2bf(v);
      }
  }
  stage_single(P1, hin, rowbase, a, tid);
  __syncthreads();

  // ---- exact f32 rowsums of the bf16 tiles (for centered-W correction) ----
  {
    int row = tid >> 2, qd = tid & 3;
    float sx = 0.f, sh = 0.f;
#pragma unroll 8
    for (int i = 0; i < 64; ++i) {
      int c = qd * 64 + i;
      int idx = ((row << 8) + c) ^ ((row & 7) << 3);
      sx += bf2f(P0[idx]);
      sh += bf2f(P1[idx]);
    }
    RSXP[qd][row] = sx; RSHP[qd][row] = sh;
  }
  __syncthreads();
  if (tid < 64) {
    RSX[tid] = RSXP[0][tid] + RSXP[1][tid] + RSXP[2][tid] + RSXP[3][tid];
    RSH[tid] = RSHP[0][tid] + RSHP[1][tid] + RSHP[2][tid] + RSHP[3][tid];
  }
  __syncthreads();

  const unsigned short* WihA = Wih + a * 768 * 256;
  const unsigned short* WhhA = Whh + a * 768 * 256;

  // ---- resetgate r = sigmoid(x@Wih_r + h@Whh_r + 0.5*(rsx+rsh) + biases) ---
  f32x4 R[4][4];
#pragma unroll
  for (int mt = 0; mt < 4; ++mt)
#pragma unroll
    for (int nt = 0; nt < 4; ++nt) R[mt][nt] = (f32x4){0.f, 0.f, 0.f, 0.f};
  mma64(P0, WihA, n0, l16, l4, R);
  mma64(P1, WhhA, n0, l16, l4, R);
#pragma unroll
  for (int nt = 0; nt < 4; ++nt) {
    int col = n0 + nt * 16 + l16;
    float bb = bih[a * 768 + col] + bhh[a * 768 + col];
#pragma unroll
    for (int mt = 0; mt < 4; ++mt)
#pragma unroll
      for (int r = 0; r < 4; ++r) {
        int row = mt * 16 + l4 * 4 + r;
        float z = R[mt][nt][r] + 0.5f * (RSX[row] + RSH[row]) + bb;
        R[mt][nt][r] = sigm(z);
      }
  }

  // ---- HN = r * (h@Whh_n + 0.5*rsh + bhh_n) ----
  f32x4 HN[4][4];
#pragma unroll
  for (int mt = 0; mt < 4; ++mt)
#pragma unroll
    for (int nt = 0; nt < 4; ++nt) HN[mt][nt] = (f32x4){0.f, 0.f, 0.f, 0.f};
  mma64(P1, WhhA + 512 * 256, n0, l16, l4, HN);
#pragma unroll
  for (int nt = 0; nt < 4; ++nt) {
    int col = n0 + nt * 16 + l16;
    float bb = bhh[a * 768 + 512 + col];
#pragma unroll
    for (int mt = 0; mt < 4; ++mt)
#pragma unroll
      for (int r = 0; r < 4; ++r) {
        int row = mt * 16 + l4 * 4 + r;
        HN[mt][nt][r] = R[mt][nt][r] * (HN[mt][nt][r] + 0.5f * RSH[row] + bb);
      }
  }

  // ---- newgate = tanh(x@Wih_n + 0.5*rsx + bih_n + HN) ----
  f32x4 NG[4][4];
#pragma unroll
  for (int mt = 0; mt < 4; ++mt)
#pragma unroll
    for (int nt = 0; nt < 4; ++nt) NG[mt][nt] = (f32x4){0.f, 0.f, 0.f, 0.f};
  mma64(P0, WihA + 512 * 256, n0, l16, l4, NG);
#pragma unroll
  for (int nt = 0; nt < 4; ++nt) {
    int col = n0 + nt * 16 + l16;
    float bb = bih[a * 768 + 512 + col];
#pragma unroll
    for (int mt = 0; mt < 4; ++mt)
#pragma unroll
      for (int r = 0; r < 4; ++r) {
        int row = mt * 16 + l4 * 4 + r;
        float z = NG[mt][nt][r] + 0.5f * RSX[row] + bb + HN[mt][nt][r];
        NG[mt][nt][r] = tanh_(z);
      }
  }

  // ---- inputgate (reuse HN as acc), combine, write h ----
#pragma unroll
  for (int mt = 0; mt < 4; ++mt)
#pragma unroll
    for (int nt = 0; nt < 4; ++nt) HN[mt][nt] = (f32x4){0.f, 0.f, 0.f, 0.f};
  mma64(P0, WihA + 256 * 256, n0, l16, l4, HN);
  mma64(P1, WhhA + 256 * 256, n0, l16, l4, HN);
#pragma unroll
  for (int nt = 0; nt < 4; ++nt) {
    int col = n0 + nt * 16 + l16;
    float bb = bih[a * 768 + 256 + col] + bhh[a * 768 + 256 + col];
#pragma unroll
    for (int mt = 0; mt < 4; ++mt)
#pragma unroll
      for (int r = 0; r < 4; ++r) {
        int row = mt * 16 + l4 * 4 + r;
        float z = HN[mt][nt][r] + 0.5f * (RSX[row] + RSH[row]) + bb;
        float ig = sigm(z);
        float hv = bf2f(P1[((row << 8) + col) ^ ((row & 7) << 3)]);
        float ng = NG[mt][nt][r];
        float h = ng + ig * (hv - ng);
        out[QSIZE + ((((rowbase + row) << 3) + a) << 8) + col] = h;
        NG[mt][nt][r] = h;                 // keep for fc2 staging
      }
  }
  __syncthreads();                          // everyone done reading P0 (x)
#pragma unroll
  for (int nt = 0; nt < 4; ++nt) {
    int col = n0 + nt * 16 + l16;
#pragma unroll
    for (int mt = 0; mt < 4; ++mt)
#pragma unroll
      for (int r = 0; r < 4; ++r) {
        int row = mt * 16 + l4 * 4 + r;
        P0[((row << 8) + col) ^ ((row & 7) << 3)] = f2bf(NG[mt][nt][r]);
      }
  }
  __syncthreads();

  // ---- q = relu(h @ W2 + b2), N padded to 32, wave w -> 16 rows ----
  f32x4 qa[2];
  qa[0] = (f32x4){0.f, 0.f, 0.f, 0.f};
  qa[1] = (f32x4){0.f, 0.f, 0.f, 0.f};
#pragma unroll
  for (int ks = 0; ks < 8; ++ks) {
    int row = w * 16 + l16;
    int idx = ((row << 8) + ks * 32 + 8 * l4) ^ ((row & 7) << 3);
    s8 af = *(const s8*)(P0 + idx);
#pragma unroll
    for (int nt = 0; nt < 2; ++nt) {
      s8 bw = *(const s8*)(W2t + ((a * 32 + nt * 16 + l16) << 8) + ks * 32 + 8 * l4);
      qa[nt] = __builtin_amdgcn_mfma_f32_16x16x32_bf16(af, bw, qa[nt], 0, 0, 0);
    }
  }
#pragma unroll
  for (int nt = 0; nt < 2; ++nt) {
    int col = nt * 16 + l16;
    if (col < 30) {
      float bb = b2[a * 30 + col];
#pragma unroll
      for (int r = 0; r < 4; ++r) {
        int row = w * 16 + l4 * 4 + r;
        out[(((rowbase + row) << 3) + a) * 30 + col] = fmaxf(qa[nt][r] + bb, 0.f);
      }
    }
  }
}

extern "C" void kernel_launch(void* const* d_in, const int* in_sizes, int n_in,
                              void* d_out, int out_size, void* d_ws, size_t ws_size,
                              hipStream_t stream) {
  const float* inputs = (const float*)d_in[0];
  const float* hidden = (const float*)d_in[1];
  const float* fc1w   = (const float*)d_in[2];
  const float* fc1b   = (const float*)d_in[3];
  const float* rihw   = (const float*)d_in[4];
  const float* rihb   = (const float*)d_in[5];
  const float* rhhw   = (const float*)d_in[6];
  const float* rhhb   = (const float*)d_in[7];
  const float* fc2w   = (const float*)d_in[8];
  const float* fc2b   = (const float*)d_in[9];
  unsigned short* ws  = (unsigned short*)d_ws;
  float* out          = (float*)d_out;

  hipLaunchKernelGGL(prep_weights, dim3(3648), dim3(256), 0, stream,
                     fc1w, rihw, rhhw, fc2w, ws);
  hipLaunchKernelGGL(fused_agent_rnn, dim3(512), dim3(256), 0, stream,
                     inputs, hidden, fc1b, rihb, rhhb, fc2b, ws, out);
}